// Round 7
// baseline (7114.017 us; speedup 1.0000x reference)
//
#include <hip/hip_runtime.h>

// B=2048, T=128, D=5, H=256. Two sequential LSTM scans.
// Round 7: gate-split 4-way across cooperating WGs, weights fully LDS-resident.
// 64 groups x 4 members = 256 WGs (1/CU). Group owns 32 batch rows; member m
// owns units [64m,64m+64) (all 4 gates): its weight quarter = 128 KB in LDS.
// Per step, members exchange 4 KB h-slices via L2 (release/acquire flags,
// 2 slots). 8 waves: 0-3 compute (one 16-unit column each), 4 publisher,
// 5-7 pullers. ~100 VGPR -> no spills (the R4-R6 killer).

typedef __bf16 bf16x8 __attribute__((ext_vector_type(8)));
typedef float f32x4 __attribute__((ext_vector_type(4)));
typedef int i32x4 __attribute__((ext_vector_type(4)));

#define MFMA16(A, B, C) __builtin_amdgcn_mfma_f32_16x16x32_bf16((A), (B), (C), 0, 0, 0)

__device__ __forceinline__ float fast_sigmoid(float x) {
  float e = __builtin_amdgcn_exp2f(-1.4426950408889634f * x);
  return __builtin_amdgcn_rcpf(1.0f + e);
}
__device__ __forceinline__ float fast_tanh(float x) {
  float e = __builtin_amdgcn_exp2f(2.8853900817779268f * x);
  return 1.0f - 2.0f * __builtin_amdgcn_rcpf(e + 1.0f);
}
__device__ __forceinline__ float lrelu(float x) { return x >= 0.0f ? x : 0.01f * x; }

// ---------------- prep ----------------
// Wpk[m][t=gate*4+us][c][lane][8]: frag = W[gate*256+m*64+us*16+(lane&15)][c*32+(lane>>4)*8+j]
__global__ void pack_w(const float* __restrict__ Whh, const float* __restrict__ Wih,
                       const float* __restrict__ bih, const float* __restrict__ bhh,
                       __bf16* __restrict__ Wpk, __bf16* __restrict__ Wihpk,
                       float* __restrict__ Bpk) {
  int lane = threadIdx.x, blk = blockIdx.x;
  if (blk < 512) {
    int m = blk >> 7, t = (blk >> 3) & 15, c = blk & 7;
    int gate = t >> 2, us = t & 3;
    int grow = gate * 256 + m * 64 + us * 16 + (lane & 15);
    int k0 = c * 32 + (lane >> 4) * 8;
    bf16x8 v;
#pragma unroll
    for (int j = 0; j < 8; ++j) v[j] = (__bf16)Whh[grow * 256 + k0 + j];
    *(bf16x8*)(Wpk + (((size_t)(m * 16 + t) * 8 + c) * 64 + lane) * 8) = v;
  } else if (blk < 528) {
    int idx = blk - 512, m = idx >> 2, gate = idx & 3, u = lane;
    int grow = gate * 256 + m * 64 + u;
    bf16x8 v;
#pragma unroll
    for (int j = 0; j < 8; ++j) v[j] = (j < 5) ? (__bf16)Wih[grow * 5 + j] : (__bf16)0.0f;
    *(bf16x8*)(Wihpk + ((size_t)(m * 4 + gate) * 64 + u) * 8) = v;
  } else {
    int d = (blk - 528) * 64 + lane;
    int m = d >> 8, gate = (d >> 6) & 3, u = d & 63;
    int grow = gate * 256 + m * 64 + u;
    Bpk[d] = bih[grow] + bhh[grow];
  }
}

__global__ void pack_misc(const float* __restrict__ Wenc, const float* __restrict__ Wout,
                          __bf16* __restrict__ Epk, __bf16* __restrict__ Od) {
  int lane = threadIdx.x, blk = blockIdx.x;
  if (blk < 128) {  // W_enc[:, :256]: 16 row-tiles x 8 chunks
    int T2 = blk >> 3, c = blk & 7;
    int row = T2 * 16 + (lane & 15), k0 = c * 32 + (lane >> 4) * 8;
    bf16x8 v;
#pragma unroll
    for (int j = 0; j < 8; ++j) v[j] = (__bf16)Wenc[row * 512 + k0 + j];
    *(bf16x8*)(Epk + (((size_t)T2 * 8 + c) * 64 + lane) * 8) = v;
  } else {  // W_out dense, row-XOR-swizzled (R5 scheme)
    for (int i = lane; i < 1280; i += 64) {
      int row = i >> 8, kk = i & 255;
      Od[row * 256 + (kk ^ (row << 3))] = (__bf16)Wout[row * 256 + kk];
    }
  }
}

// ---------------- main ----------------
// gates for this wave's 16-unit column (us), both row-tiles, all 4 gates
#define GATES(AX0, AX1)                                                            \
  {                                                                                \
    f32x4 acc0[4], acc1[4];                                                        \
    _Pragma("unroll") for (int gi = 0; gi < 4; ++gi) {                             \
      float bv = biass[gi * 64 + us * 16 + col];                                   \
      acc0[gi] = (f32x4){bv, bv, bv, bv}; acc1[gi] = acc0[gi];                     \
    }                                                                              \
    _Pragma("unroll") for (int c = 0; c < 8; ++c) {                                \
      const int r0 = col, r1 = 16 + col;                                           \
      bf16x8 a0 = *(const bf16x8*)(hbb + ((r0 * 512 + c * 64 + lgrp * 16) ^ ((r0 & 7) << 4))); \
      bf16x8 a1 = *(const bf16x8*)(hbb + ((r1 * 512 + c * 64 + lgrp * 16) ^ ((r1 & 7) << 4))); \
      _Pragma("unroll") for (int gi = 0; gi < 4; ++gi) {                           \
        bf16x8 bb = *(const bf16x8*)&wlds[gi * 4 + us][c][lane][0];                \
        acc0[gi] = MFMA16(a0, bb, acc0[gi]);                                       \
        acc1[gi] = MFMA16(a1, bb, acc1[gi]);                                       \
      }                                                                            \
    }                                                                              \
    _Pragma("unroll") for (int gi = 0; gi < 4; ++gi) {                             \
      bf16x8 bx = (bf16x8){};                                                      \
      if (lgrp == 0) bx = *(const bf16x8*)&wihs[gi][us * 16 + col][0];             \
      acc0[gi] = MFMA16(AX0, bx, acc0[gi]);                                        \
      acc1[gi] = MFMA16(AX1, bx, acc1[gi]);                                        \
    }                                                                              \
    _Pragma("unroll") for (int r = 0; r < 4; ++r) {                                \
      float ig = fast_sigmoid(acc0[0][r]), fg = fast_sigmoid(acc0[1][r]);          \
      float gg = fast_tanh(acc0[2][r]), og = fast_sigmoid(acc0[3][r]);             \
      float cn = fg * c_reg0[r] + ig * gg; c_reg0[r] = cn;                         \
      hv0[r] = og * fast_tanh(cn);                                                 \
      ig = fast_sigmoid(acc1[0][r]); fg = fast_sigmoid(acc1[1][r]);                \
      gg = fast_tanh(acc1[2][r]); og = fast_sigmoid(acc1[3][r]);                   \
      cn = fg * c_reg1[r] + ig * gg; c_reg1[r] = cn;                               \
      hv1[r] = og * fast_tanh(cn);                                                 \
    }                                                                              \
  }

#define HVWR(V0, V1)                                                               \
  _Pragma("unroll") for (int r = 0; r < 4; ++r) {                                  \
    const int row0 = lgrp * 4 + r, row1 = 16 + lgrp * 4 + r;                       \
    const int ub = m * 128 + us * 32 + col * 2;                                    \
    *(__bf16*)(hbb + ((row0 * 512 + ub) ^ ((row0 & 7) << 4))) = (__bf16)(V0);      \
    *(__bf16*)(hbb + ((row1 * 512 + ub) ^ ((row1 & 7) << 4))) = (__bf16)(V1);      \
  }

__global__ __launch_bounds__(512) void rnn_gx(
    const float* __restrict__ sk, const float* __restrict__ initx,
    const __bf16* __restrict__ WpkG, const __bf16* __restrict__ WihG, const float* __restrict__ BG,
    const __bf16* __restrict__ WpkF, const __bf16* __restrict__ WihF, const float* __restrict__ BF,
    const __bf16* __restrict__ Epk, const float* __restrict__ benc,
    const __bf16* __restrict__ Od, const float* __restrict__ bout,
    __bf16* __restrict__ hx, unsigned* __restrict__ flags,
    float* __restrict__ out) {
  __shared__ __attribute__((aligned(16))) __bf16 wlds[16][8][64][8];  // 128 KB
  __shared__ __attribute__((aligned(16))) __bf16 hb[32 * 256];        // 16 KB (swizzled)
  __shared__ __attribute__((aligned(16))) __bf16 wihs[4][64][8];      // 4 KB
  __shared__ __attribute__((aligned(16))) float biass[256];           // 1 KB
  __shared__ __attribute__((aligned(16))) __bf16 woutd[5][256];       // 2.5 KB
  __shared__ __attribute__((aligned(16))) __bf16 xts[32][8];          // 512 B

  const int tid = threadIdx.x, lane = tid & 63, wv = tid >> 6;
  const int col = lane & 15, lgrp = lane >> 4;
  const int m = blockIdx.x >> 6;   // member 0..3 (gate/unit quarter)
  const int g = blockIdx.x & 63;   // group (members same XCD: bids g+64k = g mod 8)
  const int b0 = g * 32;
  const int us = wv;  // compute waves 0..3
  char* hbb = (char*)hb;
  char* wob = (char*)woutd;
  unsigned* flagp = flags + g * 4;
  char* hxg = (char*)hx + (size_t)g * 4 * 2 * 4096;  // [member][slot][4096]

  auto stage_w = [&](const __bf16* Wm, const __bf16* Wim, const float* Bm) {
    const i32x4* s = (const i32x4*)Wm;
    i32x4* d = (i32x4*)&wlds[0][0][0][0];
    for (int i = tid; i < 8192; i += 512) d[i] = s[i];
    if (tid < 256) ((i32x4*)&wihs[0][0][0])[tid] = ((const i32x4*)Wim)[tid];
    if (tid < 256) biass[tid] = Bm[tid];
  };

  auto publish = [&](int f) {  // wv==4
    char* dst = hxg + ((size_t)m * 2 + (f & 1)) * 4096;
#pragma unroll
    for (int i = 0; i < 4; ++i) {
      int row = i * 8 + (lane >> 3), sl = lane & 7;
      i32x4 v = *(const i32x4*)(hbb + ((row * 512 + m * 128 + sl * 16) ^ ((row & 7) << 4)));
      *(i32x4*)(dst + (i * 64 + lane) * 16) = v;
    }
    __threadfence();
    if (lane == 0)
      __hip_atomic_store(flagp + m, (unsigned)f, __ATOMIC_RELEASE, __HIP_MEMORY_SCOPE_AGENT);
  };
  auto stagep = [&](int f) {  // wv in 5..7, peer = m+1..m+3 mod 4
    int p = (m + wv - 4) & 3;
    while (__hip_atomic_load(flagp + p, __ATOMIC_ACQUIRE, __HIP_MEMORY_SCOPE_AGENT) < (unsigned)f)
      __builtin_amdgcn_s_sleep(1);
    const char* src = hxg + ((size_t)p * 2 + (f & 1)) * 4096;
#pragma unroll
    for (int i = 0; i < 4; ++i) {
      int row = i * 8 + (lane >> 3), sl = lane & 7;
      i32x4 v = *(const i32x4*)(src + (i * 64 + lane) * 16);
      *(i32x4*)(hbb + ((row * 512 + p * 128 + sl * 16) ^ ((row & 7) << 4))) = v;
    }
  };

  // ---------- prologue ----------
  stage_w(WpkF + (size_t)m * 65536, WihF + (size_t)m * 2048, BF + m * 256);
  {
    i32x4 z = (i32x4){0, 0, 0, 0};
    for (int i = tid; i < 1024; i += 512) ((i32x4*)hb)[i] = z;
    if (tid < 32) ((i32x4*)&xts[0][0])[tid] = z;
  }
  float c_reg0[4] = {0.f, 0.f, 0.f, 0.f}, c_reg1[4] = {0.f, 0.f, 0.f, 0.f};
  float xc0[5], xc1[5];
  if (wv < 4 && lgrp == 0) {
    const float* p0 = sk + (size_t)(b0 + col) * 640;
    const float* p1 = sk + (size_t)(b0 + 16 + col) * 640;
#pragma unroll
    for (int d = 0; d < 5; ++d) { xc0[d] = p0[d]; xc1[d] = p1[d]; }
  }
  __syncthreads();

  // -------- encoder: 128 steps --------
#pragma unroll 1
  for (int t = 0; t < 128; ++t) {
    float hv0[4], hv1[4];
    if (wv < 4) {
      bf16x8 ax0 = (bf16x8){}, ax1 = (bf16x8){};
      if (lgrp == 0) {
#pragma unroll
        for (int d = 0; d < 5; ++d) { ax0[d] = (__bf16)xc0[d]; ax1[d] = (__bf16)xc1[d]; }
        if (t < 127) {  // prefetch x(t+1) under the MFMA chain
          const float* p0 = sk + ((size_t)(b0 + col) * 128 + t + 1) * 5;
          const float* p1 = sk + ((size_t)(b0 + 16 + col) * 128 + t + 1) * 5;
#pragma unroll
          for (int d = 0; d < 5; ++d) { xc0[d] = p0[d]; xc1[d] = p1[d]; }
        }
      }
      GATES(ax0, ax1);
    }
    __syncthreads();  // R: all h(t) reads done
    if (wv < 4) HVWR(hv0[r], hv1[r]);
    __syncthreads();  // W: own region updated
    if (wv == 4) publish(t + 1);
    else if (wv >= 5) stagep(t + 1);
    __syncthreads();  // S: h(t+1) full
  }

  // -------- transition --------
  f32x4 hacc0, hacc1;
  bf16x8 eb[8];
  float bvh = 0.f;
  if (wv < 4) {
    const int T2 = m * 4 + us;
#pragma unroll
    for (int c = 0; c < 8; ++c) eb[c] = *(const bf16x8*)(Epk + (((size_t)T2 * 8 + c) * 64 + lane) * 8);
    bvh = benc[m * 64 + us * 16 + col];
    hacc0 = (f32x4){bvh, bvh, bvh, bvh}; hacc1 = hacc0;
#pragma unroll
    for (int c = 0; c < 8; ++c) {
      const int r0 = col, r1 = 16 + col;
      bf16x8 a0 = *(const bf16x8*)(hbb + ((r0 * 512 + c * 64 + lgrp * 16) ^ ((r0 & 7) << 4)));
      bf16x8 a1 = *(const bf16x8*)(hbb + ((r1 * 512 + c * 64 + lgrp * 16) ^ ((r1 & 7) << 4)));
      hacc0 = MFMA16(a0, eb[c], hacc0);
      hacc1 = MFMA16(a1, eb[c], hacc1);
    }
  }
  __syncthreads();  // h_f reads done
  if (wv < 4) HVWR(c_reg0[r], c_reg1[r]);  // c_f into own region
  __syncthreads();  // W
  if (wv == 4) publish(129);
  else if (wv >= 5) stagep(129);
  __syncthreads();  // S: c_f full
  if (wv < 4) {
    f32x4 cacc0 = (f32x4){bvh, bvh, bvh, bvh}, cacc1 = cacc0;
#pragma unroll
    for (int c = 0; c < 8; ++c) {
      const int r0 = col, r1 = 16 + col;
      bf16x8 a0 = *(const bf16x8*)(hbb + ((r0 * 512 + c * 64 + lgrp * 16) ^ ((r0 & 7) << 4)));
      bf16x8 a1 = *(const bf16x8*)(hbb + ((r1 * 512 + c * 64 + lgrp * 16) ^ ((r1 & 7) << 4)));
      cacc0 = MFMA16(a0, eb[c], cacc0);
      cacc1 = MFMA16(a1, eb[c], cacc1);
    }
#pragma unroll
    for (int r = 0; r < 4; ++r) { c_reg0[r] = lrelu(cacc0[r]); c_reg1[r] = lrelu(cacc1[r]); }
  }
  __syncthreads();  // c_f reads done
  if (wv < 4) HVWR(lrelu(hacc0[r]), lrelu(hacc1[r]));  // gen h(0) into own region
  __syncthreads();  // W
  if (wv == 4) publish(130);
  else if (wv >= 5) stagep(130);
  __syncthreads();  // S: gen h(0) full
  // restage generator weights (all threads)
  stage_w(WpkG + (size_t)m * 65536, WihG + (size_t)m * 2048, BG + m * 256);
  if (tid < 160) ((i32x4*)&woutd[0][0])[tid] = ((const i32x4*)Od)[tid];
  float ix0[5], ix1[5];
  if (wv < 4 && lgrp == 0) {
    const float* q0 = initx + (size_t)(b0 + col) * 5;
    const float* q1 = initx + (size_t)(b0 + 16 + col) * 5;
#pragma unroll
    for (int d = 0; d < 5; ++d) { ix0[d] = q0[d]; ix1[d] = q1[d]; }
  }
  const float bo = (col < 5) ? bout[col] : 0.0f;
  const int orow = (col < 5) ? col : 0;
  __syncthreads();

  // -------- generator: iters j=0..128 (out(j-1) then gates->h(j+1)) --------
#pragma unroll 1
  for (int j = 0; j <= 128; ++j) {
    if (j > 0 && wv < 2) {  // out(j-1) = lrelu(Wout @ h(j) + b): wave wv handles row-tile rt=wv
      const int rt = wv;
      f32x4 oacc = (f32x4){bo, bo, bo, bo};
#pragma unroll
      for (int c = 0; c < 8; ++c) {
        const int rr = rt * 16 + col;
        bf16x8 ac = *(const bf16x8*)(hbb + ((rr * 512 + c * 64 + lgrp * 16) ^ ((rr & 7) << 4)));
        bf16x8 wb = *(const bf16x8*)(wob + orow * 512 + ((c * 64 + lgrp * 16) ^ (orow << 4)));
        oacc = MFMA16(ac, wb, oacc);
      }
      if (col < 5) {
#pragma unroll
        for (int r = 0; r < 4; ++r) {
          float v = lrelu(oacc[r]);
          out[((size_t)(b0 + rt * 16 + lgrp * 4 + r) * 128 + (j - 1)) * 5 + col] = v;
          xts[rt * 16 + lgrp * 4 + r][col] = (__bf16)v;  // cols 5..7 stay zero
        }
      }
    }
    __syncthreads();  // X: x(j) ready
    if (j < 128) {
      float hv0[4], hv1[4];
      if (wv < 4) {
        bf16x8 ax0 = (bf16x8){}, ax1 = (bf16x8){};
        if (lgrp == 0) {
          if (j == 0) {
#pragma unroll
            for (int d = 0; d < 5; ++d) { ax0[d] = (__bf16)ix0[d]; ax1[d] = (__bf16)ix1[d]; }
          } else {
            ax0 = *(const bf16x8*)&xts[col][0];
            ax1 = *(const bf16x8*)&xts[16 + col][0];
          }
        }
        GATES(ax0, ax1);
      }
      __syncthreads();  // R
      if (wv < 4) HVWR(hv0[r], hv1[r]);
      __syncthreads();  // W
      if (wv == 4) publish(131 + j);
      else if (wv >= 5) stagep(131 + j);
    }
    __syncthreads();  // S: h(j+1) full
  }
}

extern "C" void kernel_launch(void* const* d_in, const int* in_sizes, int n_in,
                              void* d_out, int out_size, void* d_ws, size_t ws_size,
                              hipStream_t stream) {
  const float* sk = (const float*)d_in[0];
  const float* initx = (const float*)d_in[1];
  const float* W_ih = (const float*)d_in[2];
  const float* W_hh = (const float*)d_in[3];
  const float* b_ih = (const float*)d_in[4];
  const float* b_hh = (const float*)d_in[5];
  const float* W_ih_f = (const float*)d_in[6];
  const float* W_hh_f = (const float*)d_in[7];
  const float* b_ih_f = (const float*)d_in[8];
  const float* b_hh_f = (const float*)d_in[9];
  const float* W_enc = (const float*)d_in[14];
  const float* b_enc = (const float*)d_in[15];
  const float* W_out = (const float*)d_in[16];
  const float* b_out = (const float*)d_in[17];

  char* ws = (char*)d_ws;
  __bf16* Wg = (__bf16*)(ws + 0);            // 524288
  __bf16* Wf = (__bf16*)(ws + 524288);       // 524288
  __bf16* WihG = (__bf16*)(ws + 1048576);    // 16384
  __bf16* WihF = (__bf16*)(ws + 1064960);    // 16384
  float* BG = (float*)(ws + 1081344);        // 4096
  float* BF = (float*)(ws + 1085440);        // 4096
  __bf16* Epk = (__bf16*)(ws + 1089536);     // 131072
  __bf16* Od = (__bf16*)(ws + 1220608);      // 4096 (2560 used)
  __bf16* hx = (__bf16*)(ws + 1224704);      // 2097152
  unsigned* flags = (unsigned*)(ws + 3321856);  // 1024

  hipMemsetAsync(flags, 0, 1024, stream);
  pack_w<<<544, 64, 0, stream>>>(W_hh, W_ih, b_ih, b_hh, Wg, WihG, BG);
  pack_w<<<544, 64, 0, stream>>>(W_hh_f, W_ih_f, b_ih_f, b_hh_f, Wf, WihF, BF);
  pack_misc<<<129, 64, 0, stream>>>(W_enc, W_out, Epk, Od);

  rnn_gx<<<256, 512, 0, stream>>>(
      sk, initx,
      Wg, WihG, BG,
      Wf, WihF, BF,
      Epk, b_enc,
      Od, b_out,
      hx, flags, (float*)d_out);
}

// Round 10
// 2353.592 us; speedup vs baseline: 3.0226x; 3.0226x over previous
//
#include <hip/hip_runtime.h>

// B=2048, T=128, D=5, H=256. Two sequential LSTM scans.
// Round 10: all-intrinsic MFMAs (compiler owns every hazard), accumulation
// order restored to exactly R6's passing order (chunks 0..7, then x) ->
// gate math is BIT-IDENTICAL to R6 (absmax 4.88e-4). Weight residency:
// chunks 0-3 pinned to AGPRs ("+a" asm, consumed by intrinsics -- outside
// the 128-VGPR arch budget that spilled R4-R6), chunks 4,5 LDS (128 KB),
// chunks 6,7 streamed from L2 each step (prefetched at step top).
// grid=128 x 512thr, 1 WG/CU, h in XOR-swizzled 8 KB LDS, 2 barriers/step.

typedef __bf16 bf16x8 __attribute__((ext_vector_type(8)));
typedef __bf16 bf16x4 __attribute__((ext_vector_type(4)));
typedef float f32x4 __attribute__((ext_vector_type(4)));
typedef int i32x4 __attribute__((ext_vector_type(4)));

#define MFMA16(A, B, C) __builtin_amdgcn_mfma_f32_16x16x32_bf16((A), (B), (C), 0, 0, 0)

__device__ __forceinline__ float fast_sigmoid(float x) {
  float e = __builtin_amdgcn_exp2f(-1.4426950408889634f * x);
  return __builtin_amdgcn_rcpf(1.0f + e);
}
__device__ __forceinline__ float fast_tanh(float x) {
  float e = __builtin_amdgcn_exp2f(2.8853900817779268f * x);
  return 1.0f - 2.0f * __builtin_amdgcn_rcpf(e + 1.0f);
}
__device__ __forceinline__ float lrelu(float x) { return x >= 0.0f ? x : 0.01f * x; }

__device__ __forceinline__ bf16x8 asbf(i32x4 v) {
  union { i32x4 i; bf16x8 b; } u; u.i = v; return u.b;
}

// ---------------- prep: pack weights ----------------
// Whh frag (gt,c,lane): 8 bf16 = W[g=gt*16+(lane&15)][k=c*32+(lane>>4)*8+0..7]
__global__ void pack_gates_k(const float* __restrict__ Whh, const float* __restrict__ Wih,
                             const float* __restrict__ bih, const float* __restrict__ bhh,
                             __bf16* __restrict__ wpack, __bf16* __restrict__ wih4,
                             __bf16* __restrict__ wihd4, float* __restrict__ bias) {
  int lane = threadIdx.x, blk = blockIdx.x;
  if (blk < 512) {
    int gt = blk >> 3, c = blk & 7;
    int g = gt * 16 + (lane & 15);
    int k0 = c * 32 + (lane >> 4) * 8;
    bf16x8 v;
#pragma unroll
    for (int j = 0; j < 8; ++j) v[j] = (__bf16)Whh[g * 256 + k0 + j];
    *(bf16x8*)(wpack + ((size_t)(gt * 8 + c) * 64 + lane) * 8) = v;
  } else if (blk < 528) {
    int g = (blk - 512) * 64 + lane;
    bf16x4 v;
#pragma unroll
    for (int j = 0; j < 4; ++j) v[j] = (__bf16)Wih[g * 5 + j];
    *(bf16x4*)(wih4 + (size_t)g * 4) = v;
    wihd4[g] = (__bf16)Wih[g * 5 + 4];
  } else {
    int g = (blk - 528) * 64 + lane;
    bias[g] = bih[g] + bhh[g];
  }
}

__global__ void pack_misc_k(const float* __restrict__ Wenc, const float* __restrict__ Wout,
                            __bf16* __restrict__ encpack, __bf16* __restrict__ outd) {
  int lane = threadIdx.x, blk = blockIdx.x;
  if (blk < 128) {  // W_enc[:, :256]: 16 row-tiles x 8 chunks
    int T2 = blk >> 3, c = blk & 7;
    int row = T2 * 16 + (lane & 15);
    int k0 = c * 32 + (lane >> 4) * 8;
    bf16x8 v;
#pragma unroll
    for (int j = 0; j < 8; ++j) v[j] = (__bf16)Wenc[row * 512 + k0 + j];
    *(bf16x8*)(encpack + ((size_t)(T2 * 8 + c) * 64 + lane) * 8) = v;
  } else {  // W_out (5x256) dense, row-XOR-swizzled
    for (int i = lane; i < 1280; i += 64) {
      int row = i >> 8, kk = i & 255;
      outd[row * 256 + (kk ^ (row << 3))] = (__bf16)Wout[row * 256 + kk];
    }
  }
}

// ---------------- main kernel ----------------
// one half-step: gates for tiles (q=0..3, fixed P). Chunk order = R6's
// exact order: 0..3 (AGPR wa), 4,5 (LDS), 6,7 (streamed s6/s7), x. All
// MFMAs are intrinsics -> compiler inserts all required hazard nops.
#define GATEPASS(P, AX, HVP)                                                         \
  {                                                                                  \
    const int gt0 = 0 * 16 + ut2 + (P), gt1 = 1 * 16 + ut2 + (P);                    \
    const int gt2 = 2 * 16 + ut2 + (P), gt3 = 3 * 16 + ut2 + (P);                    \
    const float bv0 = biass[gt0 * 16 + col], bv1 = biass[gt1 * 16 + col];            \
    const float bv2 = biass[gt2 * 16 + col], bv3 = biass[gt3 * 16 + col];            \
    f32x4 a0 = {bv0, bv0, bv0, bv0}, a1 = {bv1, bv1, bv1, bv1};                      \
    f32x4 a2 = {bv2, bv2, bv2, bv2}, a3 = {bv3, bv3, bv3, bv3};                      \
    _Pragma("unroll") for (int c = 0; c < 4; ++c) { /* chunks 0-3: AGPR */           \
      bf16x8 ac = *(const bf16x8*)(hbb + ((col * 512 + c * 64 + lgrp * 16) ^ xsw));  \
      a0 = MFMA16(ac, asbf(wa[(0 * 2 + (P)) * 4 + c]), a0);                          \
      a1 = MFMA16(ac, asbf(wa[(1 * 2 + (P)) * 4 + c]), a1);                          \
      a2 = MFMA16(ac, asbf(wa[(2 * 2 + (P)) * 4 + c]), a2);                          \
      a3 = MFMA16(ac, asbf(wa[(3 * 2 + (P)) * 4 + c]), a3);                          \
    }                                                                                \
    _Pragma("unroll") for (int c2 = 0; c2 < 2; ++c2) { /* chunks 4,5: LDS */         \
      bf16x8 ac = *(const bf16x8*)(hbb + ((col * 512 + (c2 + 4) * 64 + lgrp * 16) ^ xsw)); \
      a0 = MFMA16(ac, *(const bf16x8*)&wlds[c2][gt0][lane][0], a0);                  \
      a1 = MFMA16(ac, *(const bf16x8*)&wlds[c2][gt1][lane][0], a1);                  \
      a2 = MFMA16(ac, *(const bf16x8*)&wlds[c2][gt2][lane][0], a2);                  \
      a3 = MFMA16(ac, *(const bf16x8*)&wlds[c2][gt3][lane][0], a3);                  \
    }                                                                                \
    { /* chunks 6,7: streamed (prefetched at step top) */                            \
      bf16x8 ac6 = *(const bf16x8*)(hbb + ((col * 512 + 6 * 64 + lgrp * 16) ^ xsw)); \
      a0 = MFMA16(ac6, asbf(s6[P][0]), a0); a1 = MFMA16(ac6, asbf(s6[P][1]), a1);    \
      a2 = MFMA16(ac6, asbf(s6[P][2]), a2); a3 = MFMA16(ac6, asbf(s6[P][3]), a3);    \
      bf16x8 ac7 = *(const bf16x8*)(hbb + ((col * 512 + 7 * 64 + lgrp * 16) ^ xsw)); \
      a0 = MFMA16(ac7, asbf(s7[P][0]), a0); a1 = MFMA16(ac7, asbf(s7[P][1]), a1);    \
      a2 = MFMA16(ac7, asbf(s7[P][2]), a2); a3 = MFMA16(ac7, asbf(s7[P][3]), a3);    \
    }                                                                                \
    { /* x chunk last (as R6) */                                                     \
      bf16x8 b0f = {}, b1f = {}, b2f = {}, b3f = {};                                 \
      if (lgrp == 0) {                                                               \
        bf16x4 w40 = *(const bf16x4*)&wih4s[gt0 * 16 + col][0];                      \
        bf16x4 w41 = *(const bf16x4*)&wih4s[gt1 * 16 + col][0];                      \
        bf16x4 w42 = *(const bf16x4*)&wih4s[gt2 * 16 + col][0];                      \
        bf16x4 w43 = *(const bf16x4*)&wih4s[gt3 * 16 + col][0];                      \
        b0f[0]=w40[0]; b0f[1]=w40[1]; b0f[2]=w40[2]; b0f[3]=w40[3];                  \
        b1f[0]=w41[0]; b1f[1]=w41[1]; b1f[2]=w41[2]; b1f[3]=w41[3];                  \
        b2f[0]=w42[0]; b2f[1]=w42[1]; b2f[2]=w42[2]; b2f[3]=w42[3];                  \
        b3f[0]=w43[0]; b3f[1]=w43[1]; b3f[2]=w43[2]; b3f[3]=w43[3];                  \
        b0f[4]=wihd4s[gt0 * 16 + col]; b1f[4]=wihd4s[gt1 * 16 + col];                \
        b2f[4]=wihd4s[gt2 * 16 + col]; b3f[4]=wihd4s[gt3 * 16 + col];                \
      }                                                                              \
      a0 = MFMA16(AX, b0f, a0); a1 = MFMA16(AX, b1f, a1);                            \
      a2 = MFMA16(AX, b2f, a2); a3 = MFMA16(AX, b3f, a3);                            \
    }                                                                                \
    _Pragma("unroll") for (int r = 0; r < 4; ++r) {                                  \
      float ig = fast_sigmoid(a0[r]);                                                \
      float fg = fast_sigmoid(a1[r]);                                                \
      float gg = fast_tanh(a2[r]);                                                   \
      float og = fast_sigmoid(a3[r]);                                                \
      float cn = fg * c_reg[P][r] + ig * gg;                                         \
      c_reg[P][r] = cn;                                                              \
      HVP[r] = og * fast_tanh(cn);                                                   \
    }                                                                                \
  }

// prefetch streamed chunks 6,7 for both passes (16 x dwordx4, constant-indexed)
#define SPREFETCH                                                                    \
  i32x4 s6[2][4], s7[2][4];                                                          \
  _Pragma("unroll") for (int pp = 0; pp < 2; ++pp)                                   \
  _Pragma("unroll") for (int q = 0; q < 4; ++q) {                                    \
    const int gt = q * 16 + ut2 + pp;                                                \
    s6[pp][q] = Ws[(gt * 8 + 6) * 64 + lane];                                        \
    s7[pp][q] = Ws[(gt * 8 + 7) * 64 + lane];                                        \
  }

#define HWRITE2(HV)                                                                    \
  _Pragma("unroll") for (int P = 0; P < 2; ++P)                                        \
  _Pragma("unroll") for (int r = 0; r < 4; ++r) {                                      \
    const int row = lgrp * 4 + r;                                                      \
    const int u = 32 * wv + 16 * P + col;                                              \
    *(__bf16*)(hbb + ((row * 512 + u * 2) ^ ((row & 7) << 4))) = (__bf16)HV[P][r];     \
  }

__global__ __launch_bounds__(512) void rnn_ag3(
    const float* __restrict__ sk, const float* __restrict__ initx,
    const i32x4* __restrict__ Wg, const __bf16* __restrict__ Wih4g, const __bf16* __restrict__ Wihd4g,
    const float* __restrict__ Bg,
    const i32x4* __restrict__ Wf, const __bf16* __restrict__ Wih4f, const __bf16* __restrict__ Wihd4f,
    const float* __restrict__ Bf,
    const bf16x8* __restrict__ Epk, const float* __restrict__ benc,
    const __bf16* __restrict__ Od, const float* __restrict__ bout,
    float* __restrict__ out) {
  __shared__ __attribute__((aligned(16))) __bf16 wlds[2][64][64][8];  // 131072 B: chunks 4,5
  __shared__ __attribute__((aligned(16))) __bf16 wih4s[1024][4];      // 8192 B
  __shared__ __attribute__((aligned(16))) __bf16 hb[4096];            // 8192 B
  __shared__ __attribute__((aligned(16))) float biass[1024];          // 4096 B
  __shared__ __attribute__((aligned(16))) __bf16 woutd[5][256];       // 2560 B
  __shared__ __attribute__((aligned(16))) __bf16 wihd4s[1024];        // 2048 B
  __shared__ __attribute__((aligned(16))) __bf16 xts[8][16][8];       // 2048 B

  const int tid = threadIdx.x, lane = tid & 63, wv = tid >> 6;
  const int col = lane & 15, lgrp = lane >> 4;
  const int b0 = blockIdx.x * 16;
  const int ut2 = wv * 2;
  const int xsw = (col & 7) << 4;
  char* hbb = (char*)hb;
  char* wob = (char*)woutd;

  auto stage_wlds = [&](const i32x4* Wpk) {  // chunks 4,5 -> LDS
    for (int i = tid; i < 8192; i += 512) {
      int c2 = i >> 12, gt = (i >> 6) & 63, ln = i & 63;
      *(i32x4*)&wlds[c2][gt][ln][0] = Wpk[(gt * 8 + 4 + c2) * 64 + ln];
    }
  };
  auto stage_small = [&](const __bf16* w4, const __bf16* wd4, const float* Bp) {
    for (int i = tid; i < 1024; i += 512) {
      *(bf16x4*)&wih4s[i][0] = *(const bf16x4*)(w4 + (size_t)i * 4);
      wihd4s[i] = wd4[i];
      biass[i] = Bp[i];
    }
  };

  // ---------- encoder prologue ----------
  stage_wlds(Wf);
  stage_small(Wih4f, Wihd4f, Bf);
  for (int i = tid; i < 4096; i += 512) hb[i] = (__bf16)0.0f;
  for (int i = tid; i < 1024; i += 512) (&xts[0][0][0])[i] = (__bf16)0.0f;

  // W_hh chunks 0..3 -> AGPR (32 quads = 128 AGPRs/lane), consumed by intrinsics
  const i32x4* Ws = Wf;  // stream base for chunks 6,7
  i32x4 wa[32];
#pragma unroll
  for (int m = 0; m < 8; ++m) {
    const int gt = (m >> 1) * 16 + ut2 + (m & 1);
#pragma unroll
    for (int c = 0; c < 4; ++c) wa[m * 4 + c] = Wf[(gt * 8 + c) * 64 + lane];
  }
#pragma unroll
  for (int i = 0; i < 32; ++i) asm volatile("" : "+a"(wa[i]));  // pin to AGPR class

  float c_reg[2][4] = {{0.f, 0.f, 0.f, 0.f}, {0.f, 0.f, 0.f, 0.f}};
  float xc0 = 0.f, xc1 = 0.f, xc2 = 0.f, xc3 = 0.f, xc4 = 0.f;
  if (lgrp == 0) {
    const float* xp = sk + (size_t)(b0 + col) * 128 * 5;
    xc0 = xp[0]; xc1 = xp[1]; xc2 = xp[2]; xc3 = xp[3]; xc4 = xp[4];
  }
  __syncthreads();

  // -------- encoder: 128 steps --------
#pragma unroll 1
  for (int t = 0; t < 128; ++t) {
    SPREFETCH;
    bf16x8 ax = (bf16x8){};
    if (lgrp == 0) {
      ax[0] = (__bf16)xc0; ax[1] = (__bf16)xc1; ax[2] = (__bf16)xc2;
      ax[3] = (__bf16)xc3; ax[4] = (__bf16)xc4;
    }
    if (t < 127 && lgrp == 0) {  // prefetch x(t+1) under the MFMA chain
      const float* xp = sk + ((size_t)(b0 + col) * 128 + t + 1) * 5;
      xc0 = xp[0]; xc1 = xp[1]; xc2 = xp[2]; xc3 = xp[3]; xc4 = xp[4];
    }
    float hv[2][4];
    GATEPASS(0, ax, hv[0]);
    GATEPASS(1, ax, hv[1]);
    __syncthreads();  // all reads of h(t) done
    HWRITE2(hv);
    __syncthreads();  // h(t+1) visible
  }

  // -------- transition --------
  bf16x8 ah[8];
#pragma unroll
  for (int c = 0; c < 8; ++c)
    ah[c] = *(const bf16x8*)(hbb + ((col * 512 + c * 64 + lgrp * 16) ^ xsw));
  __syncthreads();
#pragma unroll
  for (int P = 0; P < 2; ++P)
#pragma unroll
    for (int r = 0; r < 4; ++r) {
      const int row = lgrp * 4 + r;
      const int u = 32 * wv + 16 * P + col;
      *(__bf16*)(hbb + ((row * 512 + u * 2) ^ ((row & 7) << 4))) = (__bf16)c_reg[P][r];
    }
  __syncthreads();
  bf16x8 acf[8];
#pragma unroll
  for (int c = 0; c < 8; ++c)
    acf[c] = *(const bf16x8*)(hbb + ((col * 512 + c * 64 + lgrp * 16) ^ xsw));
  __syncthreads();  // hb free

  float hvt[2][4];
#pragma unroll
  for (int p = 0; p < 2; ++p) {
    const int T2 = ut2 + p;
    const float bvh = benc[T2 * 16 + col];
    f32x4 hacc = {bvh, bvh, bvh, bvh};
    f32x4 cacc = {bvh, bvh, bvh, bvh};
#pragma unroll
    for (int c = 0; c < 8; ++c) {
      bf16x8 eb = Epk[(T2 * 8 + c) * 64 + lane];
      hacc = MFMA16(ah[c], eb, hacc);
      cacc = MFMA16(acf[c], eb, cacc);
    }
#pragma unroll
    for (int r = 0; r < 4; ++r) {
      hvt[p][r] = lrelu(hacc[r]);
      c_reg[p][r] = lrelu(cacc[r]);  // gen c(0)
    }
  }
  HWRITE2(hvt);  // gen h(0)

  // restage for generator
  stage_wlds(Wg);
  stage_small(Wih4g, Wihd4g, Bg);
  for (int i = tid; i < 1280; i += 512) (&woutd[0][0])[i] = Od[i];
  Ws = Wg;
#pragma unroll
  for (int m = 0; m < 8; ++m) {
    const int gt = (m >> 1) * 16 + ut2 + (m & 1);
#pragma unroll
    for (int c = 0; c < 4; ++c) wa[m * 4 + c] = Wg[(gt * 8 + c) * 64 + lane];
  }
#pragma unroll
  for (int i = 0; i < 32; ++i) asm volatile("" : "+a"(wa[i]));

  const float bo = (col < 5) ? bout[col] : 0.0f;
  bf16x8 ax = (bf16x8){};
  if (lgrp == 0) {
    const float* xp = initx + (size_t)(b0 + col) * 5;
    ax[0] = (__bf16)xp[0]; ax[1] = (__bf16)xp[1]; ax[2] = (__bf16)xp[2];
    ax[3] = (__bf16)xp[3]; ax[4] = (__bf16)xp[4];
  }
  __syncthreads();  // h(0) + gen stages visible

  // -------- generator: 128 steps --------
  const int orow = (col < 5) ? col : 0;
#pragma unroll 1
  for (int j = 0; j < 128; ++j) {
    SPREFETCH;
    float hv[2][4];
    GATEPASS(0, ax, hv[0]);
    GATEPASS(1, ax, hv[1]);
    __syncthreads();  // reads of h(j) done
    HWRITE2(hv);
    __syncthreads();  // h(j+1) visible
    // out(j) = lrelu(W_out @ h(j+1) + b_out), all waves (private x-transpose)
    f32x4 oacc = {bo, bo, bo, bo};
#pragma unroll
    for (int c = 0; c < 8; ++c) {
      bf16x8 ac = *(const bf16x8*)(hbb + ((col * 512 + c * 64 + lgrp * 16) ^ xsw));
      bf16x8 wb = *(const bf16x8*)(wob + (orow * 512 + ((c * 64 + lgrp * 16) ^ (orow << 4))));
      oacc = MFMA16(ac, wb, oacc);
    }
    if (col < 5) {
#pragma unroll
      for (int r = 0; r < 4; ++r) {
        float v = lrelu(oacc[r]);
        if (wv == 0) out[((size_t)(b0 + lgrp * 4 + r) * 128 + j) * 5 + col] = v;
        xts[wv][lgrp * 4 + r][col] = (__bf16)v;  // cols 5..7 stay zero
      }
    }
    ax = (bf16x8){};
    if (lgrp == 0) ax = *(const bf16x8*)&xts[wv][col][0];
  }
}

extern "C" void kernel_launch(void* const* d_in, const int* in_sizes, int n_in,
                              void* d_out, int out_size, void* d_ws, size_t ws_size,
                              hipStream_t stream) {
  const float* sk = (const float*)d_in[0];
  const float* initx = (const float*)d_in[1];
  const float* W_ih = (const float*)d_in[2];
  const float* W_hh = (const float*)d_in[3];
  const float* b_ih = (const float*)d_in[4];
  const float* b_hh = (const float*)d_in[5];
  const float* W_ih_f = (const float*)d_in[6];
  const float* W_hh_f = (const float*)d_in[7];
  const float* b_ih_f = (const float*)d_in[8];
  const float* b_hh_f = (const float*)d_in[9];
  const float* W_enc = (const float*)d_in[14];
  const float* b_enc = (const float*)d_in[15];
  const float* W_out = (const float*)d_in[16];
  const float* b_out = (const float*)d_in[17];

  char* ws = (char*)d_ws;
  __bf16* Wg = (__bf16*)(ws + 0);            // 524288
  __bf16* Wf = (__bf16*)(ws + 524288);       // 524288
  __bf16* Wih4g = (__bf16*)(ws + 1048576);   // 8192
  __bf16* Wihd4g = (__bf16*)(ws + 1056768);  // 2048
  __bf16* Wih4f = (__bf16*)(ws + 1058816);   // 8192
  __bf16* Wihd4f = (__bf16*)(ws + 1067008);  // 2048
  float* Bg = (float*)(ws + 1069056);        // 4096
  float* Bf = (float*)(ws + 1073152);        // 4096
  __bf16* Epk = (__bf16*)(ws + 1077248);     // 131072
  __bf16* Od = (__bf16*)(ws + 1208320);      // 2560

  pack_gates_k<<<544, 64, 0, stream>>>(W_hh, W_ih, b_ih, b_hh, Wg, Wih4g, Wihd4g, Bg);
  pack_gates_k<<<544, 64, 0, stream>>>(W_hh_f, W_ih_f, b_ih_f, b_hh_f, Wf, Wih4f, Wihd4f, Bf);
  pack_misc_k<<<129, 64, 0, stream>>>(W_enc, W_out, Epk, Od);

  rnn_ag3<<<128, 512, 0, stream>>>(
      sk, initx,
      (const i32x4*)Wg, Wih4g, Wihd4g, Bg,
      (const i32x4*)Wf, Wih4f, Wihd4f, Bf,
      (const bf16x8*)Epk, b_enc,
      Od, b_out,
      (float*)d_out);
}

// Round 11
// 1714.487 us; speedup vs baseline: 4.1494x; 1.3728x over previous
//
#include <hip/hip_runtime.h>

// B=2048, T=128, D=5, H=256. Two sequential LSTM scans.
// Round 11: deliberate streaming. No register-resident weights (R4-R10 proved
// the allocator spills anything >~128 VGPR live). Chunks 4,5 LDS-resident
// (128 KB shared); chunks 0,1,2,3,6,7 streamed from L2 every step in 8-quad
// stages (<=16 quads in flight = 64 VGPR; total pressure ~110 -> no spill).
// Chain order 0..7,x == R6/R10 -> bit-identical numerics (absmax 4.88e-4).
// grid=128 x 512thr, 1 WG/CU, h in XOR-swizzled 8 KB LDS, 2 barriers/step.

typedef __bf16 bf16x8 __attribute__((ext_vector_type(8)));
typedef __bf16 bf16x4 __attribute__((ext_vector_type(4)));
typedef float f32x4 __attribute__((ext_vector_type(4)));
typedef int i32x4 __attribute__((ext_vector_type(4)));

#define MFMA16(A, B, C) __builtin_amdgcn_mfma_f32_16x16x32_bf16((A), (B), (C), 0, 0, 0)

__device__ __forceinline__ float fast_sigmoid(float x) {
  float e = __builtin_amdgcn_exp2f(-1.4426950408889634f * x);
  return __builtin_amdgcn_rcpf(1.0f + e);
}
__device__ __forceinline__ float fast_tanh(float x) {
  float e = __builtin_amdgcn_exp2f(2.8853900817779268f * x);
  return 1.0f - 2.0f * __builtin_amdgcn_rcpf(e + 1.0f);
}
__device__ __forceinline__ float lrelu(float x) { return x >= 0.0f ? x : 0.01f * x; }

__device__ __forceinline__ bf16x8 asbf(i32x4 v) {
  union { i32x4 i; bf16x8 b; } u; u.i = v; return u.b;
}

// ---------------- prep: pack weights ----------------
// Whh frag (gt,c,lane): 8 bf16 = W[g=gt*16+(lane&15)][k=c*32+(lane>>4)*8+0..7]
__global__ void pack_gates_k(const float* __restrict__ Whh, const float* __restrict__ Wih,
                             const float* __restrict__ bih, const float* __restrict__ bhh,
                             __bf16* __restrict__ wpack, __bf16* __restrict__ wih4,
                             __bf16* __restrict__ wihd4, float* __restrict__ bias) {
  int lane = threadIdx.x, blk = blockIdx.x;
  if (blk < 512) {
    int gt = blk >> 3, c = blk & 7;
    int g = gt * 16 + (lane & 15);
    int k0 = c * 32 + (lane >> 4) * 8;
    bf16x8 v;
#pragma unroll
    for (int j = 0; j < 8; ++j) v[j] = (__bf16)Whh[g * 256 + k0 + j];
    *(bf16x8*)(wpack + ((size_t)(gt * 8 + c) * 64 + lane) * 8) = v;
  } else if (blk < 528) {
    int g = (blk - 512) * 64 + lane;
    bf16x4 v;
#pragma unroll
    for (int j = 0; j < 4; ++j) v[j] = (__bf16)Wih[g * 5 + j];
    *(bf16x4*)(wih4 + (size_t)g * 4) = v;
    wihd4[g] = (__bf16)Wih[g * 5 + 4];
  } else {
    int g = (blk - 528) * 64 + lane;
    bias[g] = bih[g] + bhh[g];
  }
}

__global__ void pack_misc_k(const float* __restrict__ Wenc, const float* __restrict__ Wout,
                            __bf16* __restrict__ encpack, __bf16* __restrict__ outd) {
  int lane = threadIdx.x, blk = blockIdx.x;
  if (blk < 128) {  // W_enc[:, :256]: 16 row-tiles x 8 chunks
    int T2 = blk >> 3, c = blk & 7;
    int row = T2 * 16 + (lane & 15);
    int k0 = c * 32 + (lane >> 4) * 8;
    bf16x8 v;
#pragma unroll
    for (int j = 0; j < 8; ++j) v[j] = (__bf16)Wenc[row * 512 + k0 + j];
    *(bf16x8*)(encpack + ((size_t)(T2 * 8 + c) * 64 + lane) * 8) = v;
  } else {  // W_out (5x256) dense, row-XOR-swizzled
    for (int i = lane; i < 1280; i += 64) {
      int row = i >> 8, kk = i & 255;
      outd[row * 256 + (kk ^ (row << 3))] = (__bf16)Wout[row * 256 + kk];
    }
  }
}

// ---------------- main kernel ----------------
// stage load: DST[q] = chunk CA frag for gate-tile q, DST[4+q] = chunk CB
#define LOADQ(DST, P, CA, CB)                                                        \
  _Pragma("unroll") for (int q = 0; q < 4; ++q) {                                    \
    const int gtq = q * 16 + ut2 + (P);                                              \
    DST[q] = Ws[(gtq * 8 + (CA)) * 64 + lane];                                       \
    DST[4 + q] = Ws[(gtq * 8 + (CB)) * 64 + lane];                                   \
  }

// one half-step: gates for tiles (q=0..3, fixed P). Chunk order 0..7,x
// (identical arithmetic to R6/R10). 0-3,6,7 streamed; 4,5 LDS.
#define GATEPASS(P, AX, HVP)                                                         \
  {                                                                                  \
    i32x4 sA[8], sB[8], sC[8];                                                       \
    LOADQ(sA, P, 0, 1);                                                              \
    LOADQ(sB, P, 2, 3);                                                              \
    const int gt0 = 0 * 16 + ut2 + (P), gt1 = 1 * 16 + ut2 + (P);                    \
    const int gt2 = 2 * 16 + ut2 + (P), gt3 = 3 * 16 + ut2 + (P);                    \
    const float bv0 = biass[gt0 * 16 + col], bv1 = biass[gt1 * 16 + col];            \
    const float bv2 = biass[gt2 * 16 + col], bv3 = biass[gt3 * 16 + col];            \
    f32x4 a0 = {bv0, bv0, bv0, bv0}, a1 = {bv1, bv1, bv1, bv1};                      \
    f32x4 a2 = {bv2, bv2, bv2, bv2}, a3 = {bv3, bv3, bv3, bv3};                      \
    { /* chunks 0,1 (sA) */                                                          \
      bf16x8 ac0 = *(const bf16x8*)(hbb + ((col * 512 + 0 * 64 + lgrp * 16) ^ xsw)); \
      a0 = MFMA16(ac0, asbf(sA[0]), a0); a1 = MFMA16(ac0, asbf(sA[1]), a1);          \
      a2 = MFMA16(ac0, asbf(sA[2]), a2); a3 = MFMA16(ac0, asbf(sA[3]), a3);          \
      bf16x8 ac1 = *(const bf16x8*)(hbb + ((col * 512 + 1 * 64 + lgrp * 16) ^ xsw)); \
      a0 = MFMA16(ac1, asbf(sA[4]), a0); a1 = MFMA16(ac1, asbf(sA[5]), a1);          \
      a2 = MFMA16(ac1, asbf(sA[6]), a2); a3 = MFMA16(ac1, asbf(sA[7]), a3);          \
    }                                                                                \
    LOADQ(sC, P, 6, 7);                                                              \
    { /* chunks 2,3 (sB) */                                                          \
      bf16x8 ac2 = *(const bf16x8*)(hbb + ((col * 512 + 2 * 64 + lgrp * 16) ^ xsw)); \
      a0 = MFMA16(ac2, asbf(sB[0]), a0); a1 = MFMA16(ac2, asbf(sB[1]), a1);          \
      a2 = MFMA16(ac2, asbf(sB[2]), a2); a3 = MFMA16(ac2, asbf(sB[3]), a3);          \
      bf16x8 ac3 = *(const bf16x8*)(hbb + ((col * 512 + 3 * 64 + lgrp * 16) ^ xsw)); \
      a0 = MFMA16(ac3, asbf(sB[4]), a0); a1 = MFMA16(ac3, asbf(sB[5]), a1);          \
      a2 = MFMA16(ac3, asbf(sB[6]), a2); a3 = MFMA16(ac3, asbf(sB[7]), a3);          \
    }                                                                                \
    _Pragma("unroll") for (int c2 = 0; c2 < 2; ++c2) { /* chunks 4,5 (LDS) */        \
      bf16x8 ac = *(const bf16x8*)(hbb + ((col * 512 + (c2 + 4) * 64 + lgrp * 16) ^ xsw)); \
      a0 = MFMA16(ac, *(const bf16x8*)&wlds[c2][gt0][lane][0], a0);                  \
      a1 = MFMA16(ac, *(const bf16x8*)&wlds[c2][gt1][lane][0], a1);                  \
      a2 = MFMA16(ac, *(const bf16x8*)&wlds[c2][gt2][lane][0], a2);                  \
      a3 = MFMA16(ac, *(const bf16x8*)&wlds[c2][gt3][lane][0], a3);                  \
    }                                                                                \
    { /* chunks 6,7 (sC) */                                                          \
      bf16x8 ac6 = *(const bf16x8*)(hbb + ((col * 512 + 6 * 64 + lgrp * 16) ^ xsw)); \
      a0 = MFMA16(ac6, asbf(sC[0]), a0); a1 = MFMA16(ac6, asbf(sC[1]), a1);          \
      a2 = MFMA16(ac6, asbf(sC[2]), a2); a3 = MFMA16(ac6, asbf(sC[3]), a3);          \
      bf16x8 ac7 = *(const bf16x8*)(hbb + ((col * 512 + 7 * 64 + lgrp * 16) ^ xsw)); \
      a0 = MFMA16(ac7, asbf(sC[4]), a0); a1 = MFMA16(ac7, asbf(sC[5]), a1);          \
      a2 = MFMA16(ac7, asbf(sC[6]), a2); a3 = MFMA16(ac7, asbf(sC[7]), a3);          \
    }                                                                                \
    { /* x chunk last */                                                             \
      bf16x8 b0f = {}, b1f = {}, b2f = {}, b3f = {};                                 \
      if (lgrp == 0) {                                                               \
        bf16x4 w40 = *(const bf16x4*)&wih4s[gt0 * 16 + col][0];                      \
        bf16x4 w41 = *(const bf16x4*)&wih4s[gt1 * 16 + col][0];                      \
        bf16x4 w42 = *(const bf16x4*)&wih4s[gt2 * 16 + col][0];                      \
        bf16x4 w43 = *(const bf16x4*)&wih4s[gt3 * 16 + col][0];                      \
        b0f[0]=w40[0]; b0f[1]=w40[1]; b0f[2]=w40[2]; b0f[3]=w40[3];                  \
        b1f[0]=w41[0]; b1f[1]=w41[1]; b1f[2]=w41[2]; b1f[3]=w41[3];                  \
        b2f[0]=w42[0]; b2f[1]=w42[1]; b2f[2]=w42[2]; b2f[3]=w42[3];                  \
        b3f[0]=w43[0]; b3f[1]=w43[1]; b3f[2]=w43[2]; b3f[3]=w43[3];                  \
        b0f[4]=wihd4s[gt0 * 16 + col]; b1f[4]=wihd4s[gt1 * 16 + col];                \
        b2f[4]=wihd4s[gt2 * 16 + col]; b3f[4]=wihd4s[gt3 * 16 + col];                \
      }                                                                              \
      a0 = MFMA16(AX, b0f, a0); a1 = MFMA16(AX, b1f, a1);                            \
      a2 = MFMA16(AX, b2f, a2); a3 = MFMA16(AX, b3f, a3);                            \
    }                                                                                \
    _Pragma("unroll") for (int r = 0; r < 4; ++r) {                                  \
      float ig = fast_sigmoid(a0[r]);                                                \
      float fg = fast_sigmoid(a1[r]);                                                \
      float gg = fast_tanh(a2[r]);                                                   \
      float og = fast_sigmoid(a3[r]);                                                \
      float cn = fg * c_reg[P][r] + ig * gg;                                         \
      c_reg[P][r] = cn;                                                              \
      HVP[r] = og * fast_tanh(cn);                                                   \
    }                                                                                \
  }

#define HWRITE2(HV)                                                                    \
  _Pragma("unroll") for (int P = 0; P < 2; ++P)                                        \
  _Pragma("unroll") for (int r = 0; r < 4; ++r) {                                      \
    const int row = lgrp * 4 + r;                                                      \
    const int u = 32 * wv + 16 * P + col;                                              \
    *(__bf16*)(hbb + ((row * 512 + u * 2) ^ ((row & 7) << 4))) = (__bf16)HV[P][r];     \
  }

__global__ __launch_bounds__(512) void rnn_st(
    const float* __restrict__ sk, const float* __restrict__ initx,
    const i32x4* __restrict__ Wg, const __bf16* __restrict__ Wih4g, const __bf16* __restrict__ Wihd4g,
    const float* __restrict__ Bg,
    const i32x4* __restrict__ Wf, const __bf16* __restrict__ Wih4f, const __bf16* __restrict__ Wihd4f,
    const float* __restrict__ Bf,
    const bf16x8* __restrict__ Epk, const float* __restrict__ benc,
    const __bf16* __restrict__ Od, const float* __restrict__ bout,
    float* __restrict__ out) {
  __shared__ __attribute__((aligned(16))) __bf16 wlds[2][64][64][8];  // 131072 B: chunks 4,5
  __shared__ __attribute__((aligned(16))) __bf16 wih4s[1024][4];      // 8192 B
  __shared__ __attribute__((aligned(16))) __bf16 hb[4096];            // 8192 B
  __shared__ __attribute__((aligned(16))) float biass[1024];          // 4096 B
  __shared__ __attribute__((aligned(16))) __bf16 woutd[5][256];       // 2560 B
  __shared__ __attribute__((aligned(16))) __bf16 wihd4s[1024];        // 2048 B
  __shared__ __attribute__((aligned(16))) __bf16 xts[8][16][8];       // 2048 B

  const int tid = threadIdx.x, lane = tid & 63, wv = tid >> 6;
  const int col = lane & 15, lgrp = lane >> 4;
  const int b0 = blockIdx.x * 16;
  const int ut2 = wv * 2;
  const int xsw = (col & 7) << 4;
  char* hbb = (char*)hb;
  char* wob = (char*)woutd;

  auto stage_wlds = [&](const i32x4* Wpk) {  // chunks 4,5 -> LDS
    for (int i = tid; i < 8192; i += 512) {
      int c2 = i >> 12, gt = (i >> 6) & 63, ln = i & 63;
      *(i32x4*)&wlds[c2][gt][ln][0] = Wpk[(gt * 8 + 4 + c2) * 64 + ln];
    }
  };
  auto stage_small = [&](const __bf16* w4, const __bf16* wd4, const float* Bp) {
    for (int i = tid; i < 1024; i += 512) {
      *(bf16x4*)&wih4s[i][0] = *(const bf16x4*)(w4 + (size_t)i * 4);
      wihd4s[i] = wd4[i];
      biass[i] = Bp[i];
    }
  };

  // ---------- encoder prologue ----------
  stage_wlds(Wf);
  stage_small(Wih4f, Wihd4f, Bf);
  for (int i = tid; i < 4096; i += 512) hb[i] = (__bf16)0.0f;
  for (int i = tid; i < 1024; i += 512) (&xts[0][0][0])[i] = (__bf16)0.0f;

  const i32x4* Ws = Wf;  // stream base (chunks 0-3,6,7)

  float c_reg[2][4] = {{0.f, 0.f, 0.f, 0.f}, {0.f, 0.f, 0.f, 0.f}};
  float xc0 = 0.f, xc1 = 0.f, xc2 = 0.f, xc3 = 0.f, xc4 = 0.f;
  if (lgrp == 0) {
    const float* xp = sk + (size_t)(b0 + col) * 128 * 5;
    xc0 = xp[0]; xc1 = xp[1]; xc2 = xp[2]; xc3 = xp[3]; xc4 = xp[4];
  }
  __syncthreads();

  // -------- encoder: 128 steps --------
#pragma unroll 1
  for (int t = 0; t < 128; ++t) {
    bf16x8 ax = (bf16x8){};
    if (lgrp == 0) {
      ax[0] = (__bf16)xc0; ax[1] = (__bf16)xc1; ax[2] = (__bf16)xc2;
      ax[3] = (__bf16)xc3; ax[4] = (__bf16)xc4;
    }
    if (t < 127 && lgrp == 0) {  // prefetch x(t+1) under the MFMA chain
      const float* xp = sk + ((size_t)(b0 + col) * 128 + t + 1) * 5;
      xc0 = xp[0]; xc1 = xp[1]; xc2 = xp[2]; xc3 = xp[3]; xc4 = xp[4];
    }
    float hv[2][4];
    GATEPASS(0, ax, hv[0]);
    GATEPASS(1, ax, hv[1]);
    __syncthreads();  // all reads of h(t) done
    HWRITE2(hv);
    __syncthreads();  // h(t+1) visible
  }

  // -------- transition --------
  bf16x8 ah[8];
#pragma unroll
  for (int c = 0; c < 8; ++c)
    ah[c] = *(const bf16x8*)(hbb + ((col * 512 + c * 64 + lgrp * 16) ^ xsw));
  __syncthreads();
#pragma unroll
  for (int P = 0; P < 2; ++P)
#pragma unroll
    for (int r = 0; r < 4; ++r) {
      const int row = lgrp * 4 + r;
      const int u = 32 * wv + 16 * P + col;
      *(__bf16*)(hbb + ((row * 512 + u * 2) ^ ((row & 7) << 4))) = (__bf16)c_reg[P][r];
    }
  __syncthreads();
  bf16x8 acf[8];
#pragma unroll
  for (int c = 0; c < 8; ++c)
    acf[c] = *(const bf16x8*)(hbb + ((col * 512 + c * 64 + lgrp * 16) ^ xsw));
  __syncthreads();  // hb free

  float hvt[2][4];
#pragma unroll
  for (int p = 0; p < 2; ++p) {
    const int T2 = ut2 + p;
    const float bvh = benc[T2 * 16 + col];
    f32x4 hacc = {bvh, bvh, bvh, bvh};
    f32x4 cacc = {bvh, bvh, bvh, bvh};
#pragma unroll
    for (int c = 0; c < 8; ++c) {
      bf16x8 eb = Epk[(T2 * 8 + c) * 64 + lane];
      hacc = MFMA16(ah[c], eb, hacc);
      cacc = MFMA16(acf[c], eb, cacc);
    }
#pragma unroll
    for (int r = 0; r < 4; ++r) {
      hvt[p][r] = lrelu(hacc[r]);
      c_reg[p][r] = lrelu(cacc[r]);  // gen c(0)
    }
  }
  HWRITE2(hvt);  // gen h(0)

  // restage for generator
  stage_wlds(Wg);
  stage_small(Wih4g, Wihd4g, Bg);
  for (int i = tid; i < 1280; i += 512) (&woutd[0][0])[i] = Od[i];
  Ws = Wg;

  const float bo = (col < 5) ? bout[col] : 0.0f;
  bf16x8 ax = (bf16x8){};
  if (lgrp == 0) {
    const float* xp = initx + (size_t)(b0 + col) * 5;
    ax[0] = (__bf16)xp[0]; ax[1] = (__bf16)xp[1]; ax[2] = (__bf16)xp[2];
    ax[3] = (__bf16)xp[3]; ax[4] = (__bf16)xp[4];
  }
  __syncthreads();  // h(0) + gen stages visible

  // -------- generator: 128 steps --------
  const int orow = (col < 5) ? col : 0;
#pragma unroll 1
  for (int j = 0; j < 128; ++j) {
    float hv[2][4];
    GATEPASS(0, ax, hv[0]);
    GATEPASS(1, ax, hv[1]);
    __syncthreads();  // reads of h(j) done
    HWRITE2(hv);
    __syncthreads();  // h(j+1) visible
    // out(j) = lrelu(W_out @ h(j+1) + b_out), all waves (private x-transpose)
    f32x4 oacc = {bo, bo, bo, bo};
#pragma unroll
    for (int c = 0; c < 8; ++c) {
      bf16x8 ac = *(const bf16x8*)(hbb + ((col * 512 + c * 64 + lgrp * 16) ^ xsw));
      bf16x8 wb = *(const bf16x8*)(wob + (orow * 512 + ((c * 64 + lgrp * 16) ^ (orow << 4))));
      oacc = MFMA16(ac, wb, oacc);
    }
    if (col < 5) {
#pragma unroll
      for (int r = 0; r < 4; ++r) {
        float v = lrelu(oacc[r]);
        if (wv == 0) out[((size_t)(b0 + lgrp * 4 + r) * 128 + j) * 5 + col] = v;
        xts[wv][lgrp * 4 + r][col] = (__bf16)v;  // cols 5..7 stay zero
      }
    }
    ax = (bf16x8){};
    if (lgrp == 0) ax = *(const bf16x8*)&xts[wv][col][0];
  }
}

extern "C" void kernel_launch(void* const* d_in, const int* in_sizes, int n_in,
                              void* d_out, int out_size, void* d_ws, size_t ws_size,
                              hipStream_t stream) {
  const float* sk = (const float*)d_in[0];
  const float* initx = (const float*)d_in[1];
  const float* W_ih = (const float*)d_in[2];
  const float* W_hh = (const float*)d_in[3];
  const float* b_ih = (const float*)d_in[4];
  const float* b_hh = (const float*)d_in[5];
  const float* W_ih_f = (const float*)d_in[6];
  const float* W_hh_f = (const float*)d_in[7];
  const float* b_ih_f = (const float*)d_in[8];
  const float* b_hh_f = (const float*)d_in[9];
  const float* W_enc = (const float*)d_in[14];
  const float* b_enc = (const float*)d_in[15];
  const float* W_out = (const float*)d_in[16];
  const float* b_out = (const float*)d_in[17];

  char* ws = (char*)d_ws;
  __bf16* Wg = (__bf16*)(ws + 0);            // 524288
  __bf16* Wf = (__bf16*)(ws + 524288);       // 524288
  __bf16* Wih4g = (__bf16*)(ws + 1048576);   // 8192
  __bf16* Wihd4g = (__bf16*)(ws + 1056768);  // 2048
  __bf16* Wih4f = (__bf16*)(ws + 1058816);   // 8192
  __bf16* Wihd4f = (__bf16*)(ws + 1067008);  // 2048
  float* Bg = (float*)(ws + 1069056);        // 4096
  float* Bf = (float*)(ws + 1073152);        // 4096
  __bf16* Epk = (__bf16*)(ws + 1077248);     // 131072
  __bf16* Od = (__bf16*)(ws + 1208320);      // 2560

  pack_gates_k<<<544, 64, 0, stream>>>(W_hh, W_ih, b_ih, b_hh, Wg, Wih4g, Wihd4g, Bg);
  pack_gates_k<<<544, 64, 0, stream>>>(W_hh_f, W_ih_f, b_ih_f, b_hh_f, Wf, Wih4f, Wihd4f, Bf);
  pack_misc_k<<<129, 64, 0, stream>>>(W_enc, W_out, Epk, Od);

  rnn_st<<<128, 512, 0, stream>>>(
      sk, initx,
      (const i32x4*)Wg, Wih4g, Wihd4g, Bg,
      (const i32x4*)Wf, Wih4f, Wihd4f, Bf,
      (const bf16x8*)Epk, b_enc,
      Od, b_out,
      (float*)d_out);
}

// Round 12
// 1131.174 us; speedup vs baseline: 6.2891x; 1.5157x over previous
//
#include <hip/hip_runtime.h>

// B=2048, T=128, D=5, H=256. Two sequential LSTM scans.
// Round 12: defeat LICM. R4-R11 all converged on the same ~50-60 MB scratch
// fingerprint because the compiler HOISTS the loop-invariant weight loads out
// of the 128-step loop and spills them (streamed and "resident" versions
// canonicalize to the same hoisted+spilled form). Fix: launder the stream
// base pointer with empty asm each iteration -> loads re-issue from L2 each
// step, no hoist, no spill. 2-buffer GATEPASS keeps in-step pressure ~105.
// Chunks 4,5 LDS-resident; 0,1,2,3,6,7 streamed. Chain order 0..7,x
// == R6/R10/R11 -> bit-identical numerics (absmax 4.88e-4).

typedef __bf16 bf16x8 __attribute__((ext_vector_type(8)));
typedef __bf16 bf16x4 __attribute__((ext_vector_type(4)));
typedef float f32x4 __attribute__((ext_vector_type(4)));
typedef int i32x4 __attribute__((ext_vector_type(4)));

#define MFMA16(A, B, C) __builtin_amdgcn_mfma_f32_16x16x32_bf16((A), (B), (C), 0, 0, 0)

__device__ __forceinline__ float fast_sigmoid(float x) {
  float e = __builtin_amdgcn_exp2f(-1.4426950408889634f * x);
  return __builtin_amdgcn_rcpf(1.0f + e);
}
__device__ __forceinline__ float fast_tanh(float x) {
  float e = __builtin_amdgcn_exp2f(2.8853900817779268f * x);
  return 1.0f - 2.0f * __builtin_amdgcn_rcpf(e + 1.0f);
}
__device__ __forceinline__ float lrelu(float x) { return x >= 0.0f ? x : 0.01f * x; }

__device__ __forceinline__ bf16x8 asbf(i32x4 v) {
  union { i32x4 i; bf16x8 b; } u; u.i = v; return u.b;
}

// ---------------- prep: pack weights ----------------
// Whh frag (gt,c,lane): 8 bf16 = W[g=gt*16+(lane&15)][k=c*32+(lane>>4)*8+0..7]
__global__ void pack_gates_k(const float* __restrict__ Whh, const float* __restrict__ Wih,
                             const float* __restrict__ bih, const float* __restrict__ bhh,
                             __bf16* __restrict__ wpack, __bf16* __restrict__ wih4,
                             __bf16* __restrict__ wihd4, float* __restrict__ bias) {
  int lane = threadIdx.x, blk = blockIdx.x;
  if (blk < 512) {
    int gt = blk >> 3, c = blk & 7;
    int g = gt * 16 + (lane & 15);
    int k0 = c * 32 + (lane >> 4) * 8;
    bf16x8 v;
#pragma unroll
    for (int j = 0; j < 8; ++j) v[j] = (__bf16)Whh[g * 256 + k0 + j];
    *(bf16x8*)(wpack + ((size_t)(gt * 8 + c) * 64 + lane) * 8) = v;
  } else if (blk < 528) {
    int g = (blk - 512) * 64 + lane;
    bf16x4 v;
#pragma unroll
    for (int j = 0; j < 4; ++j) v[j] = (__bf16)Wih[g * 5 + j];
    *(bf16x4*)(wih4 + (size_t)g * 4) = v;
    wihd4[g] = (__bf16)Wih[g * 5 + 4];
  } else {
    int g = (blk - 528) * 64 + lane;
    bias[g] = bih[g] + bhh[g];
  }
}

__global__ void pack_misc_k(const float* __restrict__ Wenc, const float* __restrict__ Wout,
                            __bf16* __restrict__ encpack, __bf16* __restrict__ outd) {
  int lane = threadIdx.x, blk = blockIdx.x;
  if (blk < 128) {  // W_enc[:, :256]: 16 row-tiles x 8 chunks
    int T2 = blk >> 3, c = blk & 7;
    int row = T2 * 16 + (lane & 15);
    int k0 = c * 32 + (lane >> 4) * 8;
    bf16x8 v;
#pragma unroll
    for (int j = 0; j < 8; ++j) v[j] = (__bf16)Wenc[row * 512 + k0 + j];
    *(bf16x8*)(encpack + ((size_t)(T2 * 8 + c) * 64 + lane) * 8) = v;
  } else {  // W_out (5x256) dense, row-XOR-swizzled
    for (int i = lane; i < 1280; i += 64) {
      int row = i >> 8, kk = i & 255;
      outd[row * 256 + (kk ^ (row << 3))] = (__bf16)Wout[row * 256 + kk];
    }
  }
}

// ---------------- main kernel ----------------
#define LOADQ(DST, P, CA, CB)                                                        \
  _Pragma("unroll") for (int q = 0; q < 4; ++q) {                                    \
    const int gtq = q * 16 + ut2 + (P);                                              \
    DST[q] = Ws[(gtq * 8 + (CA)) * 64 + lane];                                       \
    DST[4 + q] = Ws[(gtq * 8 + (CB)) * 64 + lane];                                   \
  }

// one half-step: gates for tiles (q=0..3, fixed P). Chunk order 0..7,x
// (identical arithmetic to R6/R10/R11). 0-3,6,7 streamed (2 buffers, s0
// reused for 6,7); 4,5 LDS.
#define GATEPASS(P, AX, HVP)                                                         \
  {                                                                                  \
    i32x4 s0[8], s1[8];                                                              \
    LOADQ(s0, P, 0, 1);                                                              \
    LOADQ(s1, P, 2, 3);                                                              \
    const int gt0 = 0 * 16 + ut2 + (P), gt1 = 1 * 16 + ut2 + (P);                    \
    const int gt2 = 2 * 16 + ut2 + (P), gt3 = 3 * 16 + ut2 + (P);                    \
    const float bv0 = biass[gt0 * 16 + col], bv1 = biass[gt1 * 16 + col];            \
    const float bv2 = biass[gt2 * 16 + col], bv3 = biass[gt3 * 16 + col];            \
    f32x4 a0 = {bv0, bv0, bv0, bv0}, a1 = {bv1, bv1, bv1, bv1};                      \
    f32x4 a2 = {bv2, bv2, bv2, bv2}, a3 = {bv3, bv3, bv3, bv3};                      \
    { /* chunks 0,1 (s0) */                                                          \
      bf16x8 ac0 = *(const bf16x8*)(hbb + ((col * 512 + 0 * 64 + lgrp * 16) ^ xsw)); \
      a0 = MFMA16(ac0, asbf(s0[0]), a0); a1 = MFMA16(ac0, asbf(s0[1]), a1);          \
      a2 = MFMA16(ac0, asbf(s0[2]), a2); a3 = MFMA16(ac0, asbf(s0[3]), a3);          \
      bf16x8 ac1 = *(const bf16x8*)(hbb + ((col * 512 + 1 * 64 + lgrp * 16) ^ xsw)); \
      a0 = MFMA16(ac1, asbf(s0[4]), a0); a1 = MFMA16(ac1, asbf(s0[5]), a1);          \
      a2 = MFMA16(ac1, asbf(s0[6]), a2); a3 = MFMA16(ac1, asbf(s0[7]), a3);          \
    }                                                                                \
    LOADQ(s0, P, 6, 7); /* reuse s0 for chunks 6,7 (WAR keeps pressure 64) */        \
    { /* chunks 2,3 (s1) */                                                          \
      bf16x8 ac2 = *(const bf16x8*)(hbb + ((col * 512 + 2 * 64 + lgrp * 16) ^ xsw)); \
      a0 = MFMA16(ac2, asbf(s1[0]), a0); a1 = MFMA16(ac2, asbf(s1[1]), a1);          \
      a2 = MFMA16(ac2, asbf(s1[2]), a2); a3 = MFMA16(ac2, asbf(s1[3]), a3);          \
      bf16x8 ac3 = *(const bf16x8*)(hbb + ((col * 512 + 3 * 64 + lgrp * 16) ^ xsw)); \
      a0 = MFMA16(ac3, asbf(s1[4]), a0); a1 = MFMA16(ac3, asbf(s1[5]), a1);          \
      a2 = MFMA16(ac3, asbf(s1[6]), a2); a3 = MFMA16(ac3, asbf(s1[7]), a3);          \
    }                                                                                \
    _Pragma("unroll") for (int c2 = 0; c2 < 2; ++c2) { /* chunks 4,5 (LDS) */        \
      bf16x8 ac = *(const bf16x8*)(hbb + ((col * 512 + (c2 + 4) * 64 + lgrp * 16) ^ xsw)); \
      a0 = MFMA16(ac, *(const bf16x8*)&wlds[c2][gt0][lane][0], a0);                  \
      a1 = MFMA16(ac, *(const bf16x8*)&wlds[c2][gt1][lane][0], a1);                  \
      a2 = MFMA16(ac, *(const bf16x8*)&wlds[c2][gt2][lane][0], a2);                  \
      a3 = MFMA16(ac, *(const bf16x8*)&wlds[c2][gt3][lane][0], a3);                  \
    }                                                                                \
    { /* chunks 6,7 (s0 reloaded) */                                                 \
      bf16x8 ac6 = *(const bf16x8*)(hbb + ((col * 512 + 6 * 64 + lgrp * 16) ^ xsw)); \
      a0 = MFMA16(ac6, asbf(s0[0]), a0); a1 = MFMA16(ac6, asbf(s0[1]), a1);          \
      a2 = MFMA16(ac6, asbf(s0[2]), a2); a3 = MFMA16(ac6, asbf(s0[3]), a3);          \
      bf16x8 ac7 = *(const bf16x8*)(hbb + ((col * 512 + 7 * 64 + lgrp * 16) ^ xsw)); \
      a0 = MFMA16(ac7, asbf(s0[4]), a0); a1 = MFMA16(ac7, asbf(s0[5]), a1);          \
      a2 = MFMA16(ac7, asbf(s0[6]), a2); a3 = MFMA16(ac7, asbf(s0[7]), a3);          \
    }                                                                                \
    { /* x chunk last */                                                             \
      bf16x8 b0f = {}, b1f = {}, b2f = {}, b3f = {};                                 \
      if (lgrp == 0) {                                                               \
        bf16x4 w40 = *(const bf16x4*)&wih4s[gt0 * 16 + col][0];                      \
        bf16x4 w41 = *(const bf16x4*)&wih4s[gt1 * 16 + col][0];                      \
        bf16x4 w42 = *(const bf16x4*)&wih4s[gt2 * 16 + col][0];                      \
        bf16x4 w43 = *(const bf16x4*)&wih4s[gt3 * 16 + col][0];                      \
        b0f[0]=w40[0]; b0f[1]=w40[1]; b0f[2]=w40[2]; b0f[3]=w40[3];                  \
        b1f[0]=w41[0]; b1f[1]=w41[1]; b1f[2]=w41[2]; b1f[3]=w41[3];                  \
        b2f[0]=w42[0]; b2f[1]=w42[1]; b2f[2]=w42[2]; b2f[3]=w42[3];                  \
        b3f[0]=w43[0]; b3f[1]=w43[1]; b3f[2]=w43[2]; b3f[3]=w43[3];                  \
        b0f[4]=wihd4s[gt0 * 16 + col]; b1f[4]=wihd4s[gt1 * 16 + col];                \
        b2f[4]=wihd4s[gt2 * 16 + col]; b3f[4]=wihd4s[gt3 * 16 + col];                \
      }                                                                              \
      a0 = MFMA16(AX, b0f, a0); a1 = MFMA16(AX, b1f, a1);                            \
      a2 = MFMA16(AX, b2f, a2); a3 = MFMA16(AX, b3f, a3);                            \
    }                                                                                \
    _Pragma("unroll") for (int r = 0; r < 4; ++r) {                                  \
      float ig = fast_sigmoid(a0[r]);                                                \
      float fg = fast_sigmoid(a1[r]);                                                \
      float gg = fast_tanh(a2[r]);                                                   \
      float og = fast_sigmoid(a3[r]);                                                \
      float cn = fg * c_reg[P][r] + ig * gg;                                         \
      c_reg[P][r] = cn;                                                              \
      HVP[r] = og * fast_tanh(cn);                                                   \
    }                                                                                \
  }

#define HWRITE2(HV)                                                                    \
  _Pragma("unroll") for (int P = 0; P < 2; ++P)                                        \
  _Pragma("unroll") for (int r = 0; r < 4; ++r) {                                      \
    const int row = lgrp * 4 + r;                                                      \
    const int u = 32 * wv + 16 * P + col;                                              \
    *(__bf16*)(hbb + ((row * 512 + u * 2) ^ ((row & 7) << 4))) = (__bf16)HV[P][r];     \
  }

__global__ __launch_bounds__(512) void rnn_ln(
    const float* __restrict__ sk, const float* __restrict__ initx,
    const i32x4* __restrict__ Wg, const __bf16* __restrict__ Wih4g, const __bf16* __restrict__ Wihd4g,
    const float* __restrict__ Bg,
    const i32x4* __restrict__ Wf, const __bf16* __restrict__ Wih4f, const __bf16* __restrict__ Wihd4f,
    const float* __restrict__ Bf,
    const bf16x8* __restrict__ Epk, const float* __restrict__ benc,
    const __bf16* __restrict__ Od, const float* __restrict__ bout,
    float* __restrict__ out) {
  __shared__ __attribute__((aligned(16))) __bf16 wlds[2][64][64][8];  // 131072 B: chunks 4,5
  __shared__ __attribute__((aligned(16))) __bf16 wih4s[1024][4];      // 8192 B
  __shared__ __attribute__((aligned(16))) __bf16 hb[4096];            // 8192 B
  __shared__ __attribute__((aligned(16))) float biass[1024];          // 4096 B
  __shared__ __attribute__((aligned(16))) __bf16 woutd[5][256];       // 2560 B
  __shared__ __attribute__((aligned(16))) __bf16 wihd4s[1024];        // 2048 B
  __shared__ __attribute__((aligned(16))) __bf16 xts[8][16][8];       // 2048 B

  const int tid = threadIdx.x, lane = tid & 63, wv = tid >> 6;
  const int col = lane & 15, lgrp = lane >> 4;
  const int b0 = blockIdx.x * 16;
  const int ut2 = wv * 2;
  const int xsw = (col & 7) << 4;
  char* hbb = (char*)hb;
  char* wob = (char*)woutd;

  auto stage_wlds = [&](const i32x4* Wpk) {  // chunks 4,5 -> LDS
    for (int i = tid; i < 8192; i += 512) {
      int c2 = i >> 12, gt = (i >> 6) & 63, ln = i & 63;
      *(i32x4*)&wlds[c2][gt][ln][0] = Wpk[(gt * 8 + 4 + c2) * 64 + ln];
    }
  };
  auto stage_small = [&](const __bf16* w4, const __bf16* wd4, const float* Bp) {
    for (int i = tid; i < 1024; i += 512) {
      *(bf16x4*)&wih4s[i][0] = *(const bf16x4*)(w4 + (size_t)i * 4);
      wihd4s[i] = wd4[i];
      biass[i] = Bp[i];
    }
  };

  // ---------- encoder prologue ----------
  stage_wlds(Wf);
  stage_small(Wih4f, Wihd4f, Bf);
  for (int i = tid; i < 4096; i += 512) hb[i] = (__bf16)0.0f;
  for (int i = tid; i < 1024; i += 512) (&xts[0][0][0])[i] = (__bf16)0.0f;

  const i32x4* Ws = Wf;  // stream base (chunks 0-3,6,7)

  float c_reg[2][4] = {{0.f, 0.f, 0.f, 0.f}, {0.f, 0.f, 0.f, 0.f}};
  float xc0 = 0.f, xc1 = 0.f, xc2 = 0.f, xc3 = 0.f, xc4 = 0.f;
  if (lgrp == 0) {
    const float* xp = sk + (size_t)(b0 + col) * 128 * 5;
    xc0 = xp[0]; xc1 = xp[1]; xc2 = xp[2]; xc3 = xp[3]; xc4 = xp[4];
  }
  __syncthreads();

  // -------- encoder: 128 steps --------
#pragma unroll 1
  for (int t = 0; t < 128; ++t) {
    asm volatile("" : "+s"(Ws));  // launder: loads can't be hoisted across steps
    bf16x8 ax = (bf16x8){};
    if (lgrp == 0) {
      ax[0] = (__bf16)xc0; ax[1] = (__bf16)xc1; ax[2] = (__bf16)xc2;
      ax[3] = (__bf16)xc3; ax[4] = (__bf16)xc4;
    }
    if (t < 127 && lgrp == 0) {  // prefetch x(t+1) under the MFMA chain
      const float* xp = sk + ((size_t)(b0 + col) * 128 + t + 1) * 5;
      xc0 = xp[0]; xc1 = xp[1]; xc2 = xp[2]; xc3 = xp[3]; xc4 = xp[4];
    }
    float hv[2][4];
    GATEPASS(0, ax, hv[0]);
    GATEPASS(1, ax, hv[1]);
    __syncthreads();  // all reads of h(t) done
    HWRITE2(hv);
    __syncthreads();  // h(t+1) visible
  }

  // -------- transition --------
  bf16x8 ah[8];
#pragma unroll
  for (int c = 0; c < 8; ++c)
    ah[c] = *(const bf16x8*)(hbb + ((col * 512 + c * 64 + lgrp * 16) ^ xsw));
  __syncthreads();
#pragma unroll
  for (int P = 0; P < 2; ++P)
#pragma unroll
    for (int r = 0; r < 4; ++r) {
      const int row = lgrp * 4 + r;
      const int u = 32 * wv + 16 * P + col;
      *(__bf16*)(hbb + ((row * 512 + u * 2) ^ ((row & 7) << 4))) = (__bf16)c_reg[P][r];
    }
  __syncthreads();
  bf16x8 acf[8];
#pragma unroll
  for (int c = 0; c < 8; ++c)
    acf[c] = *(const bf16x8*)(hbb + ((col * 512 + c * 64 + lgrp * 16) ^ xsw));
  __syncthreads();  // hb free

  float hvt[2][4];
#pragma unroll
  for (int p = 0; p < 2; ++p) {
    const int T2 = ut2 + p;
    const float bvh = benc[T2 * 16 + col];
    f32x4 hacc = {bvh, bvh, bvh, bvh};
    f32x4 cacc = {bvh, bvh, bvh, bvh};
#pragma unroll
    for (int c = 0; c < 8; ++c) {
      bf16x8 eb = Epk[(T2 * 8 + c) * 64 + lane];
      hacc = MFMA16(ah[c], eb, hacc);
      cacc = MFMA16(acf[c], eb, cacc);
    }
#pragma unroll
    for (int r = 0; r < 4; ++r) {
      hvt[p][r] = lrelu(hacc[r]);
      c_reg[p][r] = lrelu(cacc[r]);  // gen c(0)
    }
  }
  HWRITE2(hvt);  // gen h(0)

  // restage for generator
  stage_wlds(Wg);
  stage_small(Wih4g, Wihd4g, Bg);
  for (int i = tid; i < 1280; i += 512) (&woutd[0][0])[i] = Od[i];
  Ws = Wg;

  const float bo = (col < 5) ? bout[col] : 0.0f;
  bf16x8 ax = (bf16x8){};
  if (lgrp == 0) {
    const float* xp = initx + (size_t)(b0 + col) * 5;
    ax[0] = (__bf16)xp[0]; ax[1] = (__bf16)xp[1]; ax[2] = (__bf16)xp[2];
    ax[3] = (__bf16)xp[3]; ax[4] = (__bf16)xp[4];
  }
  __syncthreads();  // h(0) + gen stages visible

  // -------- generator: 128 steps --------
  const int orow = (col < 5) ? col : 0;
#pragma unroll 1
  for (int j = 0; j < 128; ++j) {
    asm volatile("" : "+s"(Ws));  // launder
    float hv[2][4];
    GATEPASS(0, ax, hv[0]);
    GATEPASS(1, ax, hv[1]);
    __syncthreads();  // reads of h(j) done
    HWRITE2(hv);
    __syncthreads();  // h(j+1) visible
    // out(j) = lrelu(W_out @ h(j+1) + b_out), all waves (private x-transpose)
    f32x4 oacc = {bo, bo, bo, bo};
#pragma unroll
    for (int c = 0; c < 8; ++c) {
      bf16x8 ac = *(const bf16x8*)(hbb + ((col * 512 + c * 64 + lgrp * 16) ^ xsw));
      bf16x8 wb = *(const bf16x8*)(wob + (orow * 512 + ((c * 64 + lgrp * 16) ^ (orow << 4))));
      oacc = MFMA16(ac, wb, oacc);
    }
    if (col < 5) {
#pragma unroll
      for (int r = 0; r < 4; ++r) {
        float v = lrelu(oacc[r]);
        if (wv == 0) out[((size_t)(b0 + lgrp * 4 + r) * 128 + j) * 5 + col] = v;
        xts[wv][lgrp * 4 + r][col] = (__bf16)v;  // cols 5..7 stay zero
      }
    }
    ax = (bf16x8){};
    if (lgrp == 0) ax = *(const bf16x8*)&xts[wv][col][0];
  }
}

extern "C" void kernel_launch(void* const* d_in, const int* in_sizes, int n_in,
                              void* d_out, int out_size, void* d_ws, size_t ws_size,
                              hipStream_t stream) {
  const float* sk = (const float*)d_in[0];
  const float* initx = (const float*)d_in[1];
  const float* W_ih = (const float*)d_in[2];
  const float* W_hh = (const float*)d_in[3];
  const float* b_ih = (const float*)d_in[4];
  const float* b_hh = (const float*)d_in[5];
  const float* W_ih_f = (const float*)d_in[6];
  const float* W_hh_f = (const float*)d_in[7];
  const float* b_ih_f = (const float*)d_in[8];
  const float* b_hh_f = (const float*)d_in[9];
  const float* W_enc = (const float*)d_in[14];
  const float* b_enc = (const float*)d_in[15];
  const float* W_out = (const float*)d_in[16];
  const float* b_out = (const float*)d_in[17];

  char* ws = (char*)d_ws;
  __bf16* Wg = (__bf16*)(ws + 0);            // 524288
  __bf16* Wf = (__bf16*)(ws + 524288);       // 524288
  __bf16* Wih4g = (__bf16*)(ws + 1048576);   // 8192
  __bf16* Wihd4g = (__bf16*)(ws + 1056768);  // 2048
  __bf16* Wih4f = (__bf16*)(ws + 1058816);   // 8192
  __bf16* Wihd4f = (__bf16*)(ws + 1067008);  // 2048
  float* Bg = (float*)(ws + 1069056);        // 4096
  float* Bf = (float*)(ws + 1073152);        // 4096
  __bf16* Epk = (__bf16*)(ws + 1077248);     // 131072
  __bf16* Od = (__bf16*)(ws + 1208320);      // 2560

  pack_gates_k<<<544, 64, 0, stream>>>(W_hh, W_ih, b_ih, b_hh, Wg, Wih4g, Wihd4g, Bg);
  pack_gates_k<<<544, 64, 0, stream>>>(W_hh_f, W_ih_f, b_ih_f, b_hh_f, Wf, Wih4f, Wihd4f, Bf);
  pack_misc_k<<<129, 64, 0, stream>>>(W_enc, W_out, Epk, Od);

  rnn_ln<<<128, 512, 0, stream>>>(
      sk, initx,
      (const i32x4*)Wg, Wih4g, Wihd4g, Bg,
      (const i32x4*)Wf, Wih4f, Wihd4f, Bf,
      (const bf16x8*)Epk, b_enc,
      Od, b_out,
      (float*)d_out);
}